// Round 15
// baseline (534.860 us; speedup 1.0000x reference)
//
#include <hip/hip_runtime.h>
#include <math.h>

// ---- problem constants ----
#define NM 50000
#define ND 10000
#define NA 25000
#define E_DM 150000
#define E_AM 300000
#define E_TOT (E_DM + E_AM)
#define HID 256
#define HEADS 8
#define HD 32
#define FIN 1024
#define SCALE 0.17677669529663687f  // 1/sqrt(32)

typedef __attribute__((ext_vector_type(8))) short short8;
typedef __attribute__((ext_vector_type(4))) float f32x4;

typedef __attribute__((address_space(1))) const unsigned char gas_u8;
typedef __attribute__((address_space(3))) unsigned char las_u8;

// async global->LDS 16B: global per-lane address, LDS wave-uniform base (+lane*16 by HW)
__device__ __forceinline__ void gload16(const void* g, void* l) {
    gas_u8* gp = (gas_u8*)(unsigned long long)(uintptr_t)g;
    las_u8* lp = (las_u8*)(unsigned int)(uintptr_t)l;
    __builtin_amdgcn_global_load_lds((const __attribute__((address_space(1))) void*)gp,
                                     (__attribute__((address_space(3))) void*)lp, 16, 0, 0);
}

// RNE f32 -> bf16
__device__ __forceinline__ unsigned int pk_bf16(float x, float y) {
    unsigned int a = __float_as_uint(x), b = __float_as_uint(y);
    a += 0x7FFFu + ((a >> 16) & 1u);
    b += 0x7FFFu + ((b >> 16) & 1u);
    return (a >> 16) | (b & 0xFFFF0000u);
}
__device__ __forceinline__ unsigned short to_bf16(float x) {
    unsigned int a = __float_as_uint(x);
    a += 0x7FFFu + ((a >> 16) & 1u);
    return (unsigned short)(a >> 16);
}
__device__ __forceinline__ float bf2f(unsigned short u) {
    return __uint_as_float(((unsigned int)u) << 16);
}

// ---- fold per-head relation matrix into W (4 descs in one launch) ----
struct F4 { const float* W[4]; const float* b[4]; const float* a[4]; float* Wf[4]; float* bf[4]; };
__global__ void fold_w4(F4 f4) {
    int di = blockIdx.y;
    const float* W = f4.W[di]; const float* b = f4.b[di]; const float* a = f4.a[di];
    float* Wf = f4.Wf[di]; float* bf = f4.bf[di];
    int c = threadIdx.x;
    int h = c >> 5, f = c & 31;
    int r = blockIdx.x;
    float acc = 0.f;
    if (r < HID) {
        #pragma unroll
        for (int d = 0; d < HD; ++d)
            acc += W[r * HID + h * HD + d] * a[(h * HD + d) * HD + f];
        Wf[r * HID + c] = acc;
    } else {
        #pragma unroll
        for (int d = 0; d < HD; ++d)
            acc += b[h * HD + d] * a[(h * HD + d) * HD + f];
        bf[c] = acc;
    }
}

// ---- pack W fp32 [K][256] -> bf16 fragment order [K/32][16 subtile][64 lane][8] ----
struct PDesc { const float* W; unsigned short* out; int K; int b0; };
struct PMulti { PDesc d[9]; int nd; };
__global__ void wt_pack(PMulti pm) {
    int bid = blockIdx.x; int di = 0;
    #pragma unroll
    for (int i = 1; i < 9; ++i) if (i < pm.nd && bid >= pm.d[i].b0) di = i;
    PDesc p = pm.d[di];
    int kstep = bid - p.b0;
    int t = threadIdx.x;
    #pragma unroll
    for (int i = 0; i < 32; ++i) {
        int idx = i * 256 + t;
        int n0 = idx >> 9, r = idx & 511, lane = r >> 3, j = r & 7;
        int k = kstep * 32 + (lane >> 4) * 8 + j;
        int c = n0 * 16 + (lane & 15);
        p.out[(size_t)kstep * 8192 + idx] = to_bf16(p.W[(size_t)k * HID + c]);
    }
}

// ---- multi-descriptor MFMA GEMM with fused second-GEMM / classifier epilogue ----
// Main: C[M,256] = A[M,K]@B + bias (BM=64, BN=256, 8 waves, B dbuf via gload_lds
// 2x16KB, A dbuf 2x4KB, one __syncthreads per K-step).
// Epilogue (non-cls): scatter biased h-tile (bf16, fragment order) into LDS;
//   optional coalesced C write via LDS read-back; second GEMM(s) vs fragment-
//   packed B2/B3 with register-prefetch pipelining (p[4] one-step-ahead).
// Epilogue (cls): fold out-tile into d_out via fp32 partials + shfl reduce.
struct GDesc {
    const void* A; const unsigned short* Bt; const float* bias; void* C;
    const void* hskip; const float* gate;
    const unsigned short* Bt2; const float* bias2; void* C2;
    const unsigned short* Bt3; const float* bias3; void* C3;
    int M; int K; int epi; int obf; int abf; int cls; int b0;
};
struct GMulti { GDesc d[5]; int nd; };

#define GBM 64

__launch_bounds__(512, 8)
__global__ void gemm_mfma(GMulti mu) {
    __shared__ __align__(16) unsigned char smem[40960];
    unsigned short* sB0 = (unsigned short*)smem;            // 8192 elems (16KB)
    unsigned short* sB1 = sB0 + 8192;
    unsigned short* sA0 = (unsigned short*)(smem + 32768);  // 2048 elems (4KB)
    unsigned short* sA1 = sA0 + 2048;
    unsigned short* sHf = (unsigned short*)smem;            // 2nd-gemm A frags (32KB)
    float* arr = (float*)smem;                              // cls partials [2][64][4]

    int bid = blockIdx.x;
    int di = 0;
    #pragma unroll
    for (int i = 1; i < 5; ++i)
        if (i < mu.nd && bid >= mu.d[i].b0) di = i;
    GDesc g = mu.d[di];
    int bm = (bid - g.b0) * GBM;
    int M = g.M, K = g.K;

    int t = threadIdx.x;
    int lane = t & 63;
    int w = t >> 6;               // 0..7
    int wp = w >> 1;              // row subtile 0..3
    int ch = w & 1;               // col half 0..1
    int l16 = lane & 15;

    // fp32 A staging indices: thread t fills half a fragment slot
    int slot = t >> 1;            // 0..255
    int ss_ = slot >> 6;
    int sl  = slot & 63;
    int arow_f = bm + ss_ * 16 + (sl & 15);
    int ak0    = (sl >> 4) * 8 + (t & 1) * 4;
    const float* Ap = nullptr;
    const unsigned short* Abp = nullptr;
    if (g.abf) {
        if (w < 4) {
            int r = bm + w * 16 + l16;
            Abp = (const unsigned short*)g.A + (size_t)min(r, M - 1) * K + ((lane >> 4) * 8);
        }
    } else {
        Ap = (const float*)g.A + (size_t)min(arow_f, M - 1) * K + ak0;
    }

    f32x4 acc[8];
    #pragma unroll
    for (int n = 0; n < 8; ++n) acc[n] = (f32x4)(0.f);

    int nk = K >> 5;
    // prologue: stage step 0 into buf 0
    {
        const unsigned short* gB = g.Bt;
        gload16(gB + w * 512 + lane * 8, sB0 + w * 512);
        gload16(gB + (w + 8) * 512 + lane * 8, sB0 + (w + 8) * 512);
        if (g.abf) {
            if (w < 4) gload16(Abp, sA0 + w * 512);
        } else {
            float4 f = *(const float4*)(Ap);
            uint2 pk = make_uint2(pk_bf16(f.x, f.y), pk_bf16(f.z, f.w));
            *(uint2*)&sA0[slot * 8 + (t & 1) * 4] = pk;
        }
    }
    __syncthreads();

    int cur = 0;
    for (int ks = 0; ks < nk; ++ks) {
        unsigned short* sBc = cur ? sB1 : sB0;
        unsigned short* sAc = cur ? sA1 : sA0;
        unsigned short* dB  = cur ? sB0 : sB1;
        unsigned short* dA  = cur ? sA0 : sA1;
        bool pf = (ks + 1 < nk);
        float4 f;
        if (pf) {
            const unsigned short* gB = g.Bt + (size_t)(ks + 1) * 8192;
            gload16(gB + w * 512 + lane * 8, dB + w * 512);
            gload16(gB + (w + 8) * 512 + lane * 8, dB + (w + 8) * 512);
            if (g.abf) {
                if (w < 4) gload16(Abp + (ks + 1) * 32, dA + w * 512);
            } else {
                f = *(const float4*)(Ap + (ks + 1) * 32);
            }
        }
        short8 af = *(const short8*)&sAc[(wp * 64 + lane) * 8];
        short8 bfr[8];
        #pragma unroll
        for (int n = 0; n < 8; ++n)
            bfr[n] = *(const short8*)&sBc[((ch * 8 + n) * 64 + lane) * 8];
        #pragma unroll
        for (int n = 0; n < 8; ++n)
            acc[n] = __builtin_amdgcn_mfma_f32_16x16x32_bf16(af, bfr[n], acc[n], 0, 0, 0);
        if (pf && !g.abf) {
            uint2 pk = make_uint2(pk_bf16(f.x, f.y), pk_bf16(f.z, f.w));
            *(uint2*)&dA[slot * 8 + (t & 1) * 4] = pk;
        }
        __syncthreads();
        cur ^= 1;
    }

    // ---- epilogue ----
    float beta = 0.f;
    if (g.epi) beta = 1.f / (1.f + expf(-g.gate[0]));
    int r0 = bm + wp * 16 + ((lane >> 4) << 2);

    if (g.cls) {
        float pcl[4][4];
        #pragma unroll
        for (int j = 0; j < 4; ++j)
            #pragma unroll
            for (int c = 0; c < 4; ++c) pcl[j][c] = 0.f;
        #pragma unroll
        for (int n = 0; n < 8; ++n) {
            int col = ch * 128 + n * 16 + l16;
            float4 wv = *(const float4*)(g.bias2 + col * 4);   // W_out row
            #pragma unroll
            for (int j = 0; j < 4; ++j) {
                int grow = r0 + j;
                float v = acc[n][j] + g.bias[col];
                if (g.epi) {
                    float x = v;
                    float gl = 0.5f * x * (1.f + tanhf(0.7978845608028654f * (x + 0.044715f * x * x * x)));
                    float hv = bf2f(((const unsigned short*)g.hskip)[(size_t)min(grow, M - 1) * HID + col]);
                    v = beta * gl + (1.f - beta) * hv;
                }
                pcl[j][0] += v * wv.x; pcl[j][1] += v * wv.y;
                pcl[j][2] += v * wv.z; pcl[j][3] += v * wv.w;
            }
        }
        #pragma unroll
        for (int s = 1; s < 16; s <<= 1) {
            #pragma unroll
            for (int j = 0; j < 4; ++j)
                #pragma unroll
                for (int c = 0; c < 4; ++c)
                    pcl[j][c] += __shfl_xor(pcl[j][c], s);
        }
        if (l16 == 0) {
            int rb = wp * 16 + ((lane >> 4) << 2);
            #pragma unroll
            for (int j = 0; j < 4; ++j)
                #pragma unroll
                for (int c = 0; c < 4; ++c)
                    arr[((ch * 64) + rb + j) * 4 + c] = pcl[j][c];
        }
        __syncthreads();
        if (t < 256) {
            int row = t >> 2, c = t & 3;
            int grow = bm + row;
            if (grow < M) {
                float s = arr[(0 * 64 + row) * 4 + c] + arr[(1 * 64 + row) * 4 + c] + g.bias3[c];
                ((float*)g.C2)[(size_t)grow * 4 + c] = s;
            }
        }
        return;
    }

    // scatter biased h-tile into LDS fragment order
    #pragma unroll
    for (int n = 0; n < 8; ++n) {
        int col = ch * 128 + n * 16 + l16;
        #pragma unroll
        for (int j = 0; j < 4; ++j) {
            float v = acc[n][j] + g.bias[col];
            if (g.epi) {
                int grow = r0 + j;
                float x = v;
                float gl = 0.5f * x * (1.f + tanhf(0.7978845608028654f * (x + 0.044715f * x * x * x)));
                float hv = bf2f(((const unsigned short*)g.hskip)[(size_t)min(grow, M - 1) * HID + col]);
                v = beta * gl + (1.f - beta) * hv;
            }
            int ks2 = ch * 4 + (n >> 1);
            int gg = ((n & 1) << 1) | ((lane & 15) >> 3);
            int l = ((lane >> 4) << 2) + j + (gg << 4);
            sHf[(((ks2 * 4) + wp) * 64 + l) * 8 + (lane & 7)] = to_bf16(v);
        }
    }
    __syncthreads();   // h-tile fragments visible to all waves

    // coalesced C (h) write from sHf: 4 x (linear ds_read_b128 + 16B store)
    if (g.C) {
        #pragma unroll
        for (int it = 0; it < 4; ++it) {
            int c = t + it * 512;
            int ks2 = c >> 8;
            int wp_ = (c >> 6) & 3;
            int l = c & 63;
            int grow = bm + wp_ * 16 + (l & 15);
            uint4 vv = *(const uint4*)&sHf[c * 8];
            if (grow < M)
                *(uint4*)((unsigned short*)g.C + (size_t)grow * HID + ks2 * 32 + (l >> 4) * 8) = vv;
        }
    }

    if (g.Bt2) {
        #pragma unroll 1
        for (int o = 0; o < 2; ++o) {
            const unsigned short* B2 = o ? g.Bt3 : g.Bt2;
            if (!B2) break;
            const float* bias2 = o ? g.bias3 : g.bias2;
            unsigned short* C2 = (unsigned short*)(o ? g.C3 : g.C2);
            #pragma unroll
            for (int n = 0; n < 8; ++n) acc[n] = (f32x4)(0.f);   // reuse main acc regs
            const unsigned short* Bw = B2 + (size_t)((ch * 8) * 64 + lane) * 8;
            short8 p[4];
            #pragma unroll
            for (int i = 0; i < 4; ++i)
                p[i] = *(const short8*)(Bw + (size_t)(i * 64) * 8);
            #pragma unroll
            for (int ks = 0; ks < 8; ++ks) {
                short8 qv[4];
                #pragma unroll
                for (int i = 0; i < 4; ++i)
                    qv[i] = *(const short8*)(Bw + (size_t)ks * 8192 + (size_t)((4 + i) * 64) * 8);
                short8 af2 = *(const short8*)&sHf[(((ks * 4) + wp) * 64 + lane) * 8];
                #pragma unroll
                for (int i = 0; i < 4; ++i)
                    acc[i] = __builtin_amdgcn_mfma_f32_16x16x32_bf16(af2, p[i], acc[i], 0, 0, 0);
                if (ks < 7) {
                    #pragma unroll
                    for (int i = 0; i < 4; ++i)
                        p[i] = *(const short8*)(Bw + (size_t)(ks + 1) * 8192 + (size_t)(i * 64) * 8);
                }
                #pragma unroll
                for (int i = 0; i < 4; ++i)
                    acc[4 + i] = __builtin_amdgcn_mfma_f32_16x16x32_bf16(af2, qv[i], acc[4 + i], 0, 0, 0);
            }
            #pragma unroll
            for (int n = 0; n < 8; ++n) {
                int col = ch * 128 + n * 16 + l16;
                #pragma unroll
                for (int j = 0; j < 4; ++j) {
                    int grow = r0 + j;
                    if (grow < M)
                        C2[(size_t)grow * HID + col] = to_bf16(acc[n][j] + bias2[col]);
                }
            }
        }
    }
}

// ---- CSR build ----
__global__ void hist_deg(const int* __restrict__ dA, const int* __restrict__ dB,
                         int* __restrict__ deg) {
    int i = blockIdx.x * 256 + threadIdx.x;
    if (i < E_DM) atomicAdd(&deg[dA[i]], 1);
    else if (i < E_TOT) atomicAdd(&deg[dB[i - E_DM]], 1);
}

__global__ void scan_pass1(const int* __restrict__ deg, int* __restrict__ bsum) {
    __shared__ int s[256];
    int b = blockIdx.x, t = threadIdx.x;
    int i = b * 256 + t;
    int v = (i < NM) ? deg[i] : 0;
    s[t] = v; __syncthreads();
    for (int off = 128; off > 0; off >>= 1) {
        if (t < off) s[t] += s[t + off];
        __syncthreads();
    }
    if (t == 0) bsum[b] = s[0];
}

__global__ void scan_pass2(const int* __restrict__ bsum, int* __restrict__ boff, int nb) {
    __shared__ int s[256];
    int t = threadIdx.x;
    int v = (t < nb) ? bsum[t] : 0;
    s[t] = v; __syncthreads();
    for (int off = 1; off < 256; off <<= 1) {
        int x = (t >= off) ? s[t - off] : 0;
        __syncthreads();
        s[t] += x;
        __syncthreads();
    }
    if (t < nb) boff[t] = s[t] - v;   // exclusive
}

__global__ void scan_pass3(const int* __restrict__ deg, const int* __restrict__ boff,
                           int* __restrict__ rowptr, int* __restrict__ cursor) {
    __shared__ int s[256];
    int b = blockIdx.x, t = threadIdx.x, i = b * 256 + t;
    int v = (i < NM) ? deg[i] : 0;
    s[t] = v; __syncthreads();
    for (int off = 1; off < 256; off <<= 1) {
        int x = (t >= off) ? s[t - off] : 0;
        __syncthreads();
        s[t] += x;
        __syncthreads();
    }
    int excl = s[t] - v + boff[b];
    if (i < NM) { rowptr[i] = excl; cursor[i] = excl; }
    if (i == 0) rowptr[NM] = E_TOT;
}

__global__ void fill_adj(const int* __restrict__ sA, const int* __restrict__ dA,
                         const int* __restrict__ sB, const int* __restrict__ dB,
                         int* __restrict__ cursor, int* __restrict__ adj) {
    int i = blockIdx.x * 256 + threadIdx.x;
    int d, entry;
    if (i < E_DM)      { d = dA[i];        entry = sA[i]; }
    else if (i < E_TOT){ int j = i - E_DM; d = dB[j]; entry = (sB[j] + ND) | (1 << 16); }
    else return;
    int pos = atomicAdd(&cursor[d], 1);
    adj[pos] = entry;
}

// ---- fused per-destination attention aggregation: one wave per node (bf16 q/k/v, bf16 agg out) ----
__launch_bounds__(256)
__global__ void agg_fused(const int* __restrict__ rowptr, const int* __restrict__ adj,
                          const unsigned short* __restrict__ q, const unsigned short* __restrict__ kt_all,
                          const unsigned short* __restrict__ vt_all,
                          const float* __restrict__ p_dm, const float* __restrict__ p_am,
                          unsigned short* __restrict__ agg) {
    int d = blockIdx.x * 4 + (threadIdx.x >> 6);
    if (d >= NM) return;
    int lane = threadIdx.x & 63;
    int h = lane >> 3;                       // 8 lanes per head, 4 dims per lane
    int start = rowptr[d], end = rowptr[d + 1];
    uint2 qu = *(const uint2*)(q + (size_t)d * HID + lane * 4);
    float q0 = __uint_as_float(qu.x << 16), q1 = __uint_as_float(qu.x & 0xFFFF0000u);
    float q2 = __uint_as_float(qu.y << 16), q3 = __uint_as_float(qu.y & 0xFFFF0000u);
    float pr0 = p_dm[h] * SCALE, pr1 = p_am[h] * SCALE;
    float m = -INFINITY, den = 0.f, a0 = 0.f, a1 = 0.f, a2 = 0.f, a3 = 0.f;
    for (int i = start; i < end; ++i) {
        int e = adj[i];
        int sr = e & 0xFFFF;
        uint2 ku = *(const uint2*)(kt_all + (size_t)sr * HID + lane * 4);
        float k0 = __uint_as_float(ku.x << 16), k1 = __uint_as_float(ku.x & 0xFFFF0000u);
        float k2 = __uint_as_float(ku.y << 16), k3 = __uint_as_float(ku.y & 0xFFFF0000u);
        float prod = q0 * k0 + q1 * k1 + q2 * k2 + q3 * k3;
        prod += __shfl_xor(prod, 1);
        prod += __shfl_xor(prod, 2);
        prod += __shfl_xor(prod, 4);
        float a = prod * ((e >> 16) ? pr1 : pr0);
        float mn = fmaxf(m, a);
        float c  = __expf(m - mn);
        float ex = __expf(a - mn);
        uint2 vu = *(const uint2*)(vt_all + (size_t)sr * HID + lane * 4);
        float v0 = __uint_as_float(vu.x << 16), v1 = __uint_as_float(vu.x & 0xFFFF0000u);
        float v2 = __uint_as_float(vu.y << 16), v3 = __uint_as_float(vu.y & 0xFFFF0000u);
        den = den * c + ex;
        a0 = a0 * c + ex * v0; a1 = a1 * c + ex * v1;
        a2 = a2 * c + ex * v2; a3 = a3 * c + ex * v3;
        m = mn;
    }
    float inv = (end > start) ? 1.f / den : 0.f;
    *(uint2*)(agg + (size_t)d * HID + lane * 4) =
        make_uint2(pk_bf16(a0 * inv, a1 * inv), pk_bf16(a2 * inv, a3 * inv));
}

extern "C" void kernel_launch(void* const* d_in, const int* in_sizes, int n_in,
                              void* d_out, int out_size, void* d_ws, size_t ws_size,
                              hipStream_t stream) {
    (void)in_sizes; (void)n_in; (void)out_size; (void)ws_size;
    const float* x_movie    = (const float*)d_in[0];
    const float* x_director = (const float*)d_in[1];
    const float* x_actor    = (const float*)d_in[2];
    const int*   e_dm_src = (const int*)d_in[8];
    const int*   e_dm_dst = (const int*)d_in[9];
    const float* a_dm     = (const float*)d_in[10];
    const float* m_dm     = (const float*)d_in[11];
    const float* p_dm     = (const float*)d_in[12];
    const int*   e_am_src = (const int*)d_in[18];
    const int*   e_am_dst = (const int*)d_in[19];
    const float* a_am     = (const float*)d_in[20];
    const float* m_am     = (const float*)d_in[21];
    const float* p_am     = (const float*)d_in[22];
    const float* W_in_m = (const float*)d_in[23];
    const float* b_in_m = (const float*)d_in[24];
    const float* Wq_m   = (const float*)d_in[27];
    const float* bq_m   = (const float*)d_in[28];
    const float* Wa_m   = (const float*)d_in[31];
    const float* ba_m   = (const float*)d_in[32];
    const float* skip_m = (const float*)d_in[33];
    const float* W_in_d = (const float*)d_in[34];
    const float* b_in_d = (const float*)d_in[35];
    const float* Wk_d   = (const float*)d_in[36];
    const float* bk_d   = (const float*)d_in[37];
    const float* Wv_d   = (const float*)d_in[40];
    const float* bv_d   = (const float*)d_in[41];
    const float* W_in_a = (const float*)d_in[45];
    const float* b_in_a = (const float*)d_in[46];
    const float* Wk_a   = (const float*)d_in[47];
    const float* bk_a   = (const float*)d_in[48];
    const float* Wv_a   = (const float*)d_in[51];
    const float* bv_a   = (const float*)d_in[52];
    const float* W_out  = (const float*)d_in[56];
    const float* b_out  = (const float*)d_in[57];

    // ---- workspace layout (byte cursor, 256B aligned) ----
    char* base = (char*)d_ws;
    size_t off = 0;
    auto alloc = [&](size_t bytes) -> void* {
        void* p = base + off;
        off = (off + bytes + 255) & ~(size_t)255;
        return p;
    };
    unsigned short* h_m = (unsigned short*)alloc((size_t)NM * HID * 2);   // bf16
    unsigned short* q_m = (unsigned short*)alloc((size_t)NM * HID * 2);   // bf16
    unsigned short* agg = (unsigned short*)alloc((size_t)NM * HID * 2);   // bf16
    unsigned short* kt_all = (unsigned short*)alloc((size_t)(ND + NA) * HID * 2);
    unsigned short* vt_all = (unsigned short*)alloc((size_t)(ND + NA) * HID * 2);
    float* Wf     = (float*)alloc(4 * (size_t)HID * HID * 4);
    float* bf     = (float*)alloc(4 * (size_t)HID * 4);
    int* deg      = (int*)alloc(NM * 4);
    int* rowptr   = (int*)alloc((NM + 1) * 4);
    int* cursor   = (int*)alloc(NM * 4);
    int* bsum     = (int*)alloc(256 * 4);
    int* boff     = (int*)alloc(256 * 4);
    int* adj      = (int*)alloc((size_t)E_TOT * 4);
    unsigned short* Bt_in_m = (unsigned short*)alloc((size_t)256 * 1024 * 2);
    unsigned short* Bt_in_d = (unsigned short*)alloc((size_t)256 * 1024 * 2);
    unsigned short* Bt_in_a = (unsigned short*)alloc((size_t)256 * 1024 * 2);
    unsigned short* Bt_q_m  = (unsigned short*)alloc((size_t)256 * 256 * 2);
    unsigned short* Bt_k_dm = (unsigned short*)alloc((size_t)256 * 256 * 2);
    unsigned short* Bt_v_dm = (unsigned short*)alloc((size_t)256 * 256 * 2);
    unsigned short* Bt_k_am = (unsigned short*)alloc((size_t)256 * 256 * 2);
    unsigned short* Bt_v_am = (unsigned short*)alloc((size_t)256 * 256 * 2);
    unsigned short* Bt_a_m  = (unsigned short*)alloc((size_t)256 * 256 * 2);

    unsigned short* kt_dm = kt_all;
    unsigned short* kt_am = kt_all + (size_t)ND * HID;
    unsigned short* vt_dm = vt_all;
    unsigned short* vt_am = vt_all + (size_t)ND * HID;

    float* Wf_k_dm = Wf + 0 * HID * HID;  float* bf_k_dm = bf + 0 * HID;
    float* Wf_v_dm = Wf + 1 * HID * HID;  float* bf_v_dm = bf + 1 * HID;
    float* Wf_k_am = Wf + 2 * HID * HID;  float* bf_k_am = bf + 2 * HID;
    float* Wf_v_am = Wf + 3 * HID * HID;  float* bf_v_am = bf + 3 * HID;

    // ---- CSR build ----
    hipMemsetAsync(deg, 0, NM * sizeof(int), stream);
    hist_deg<<<(E_TOT + 255) / 256, 256, 0, stream>>>(e_dm_dst, e_am_dst, deg);
    int nb = (NM + 255) / 256;  // 196
    scan_pass1<<<nb, 256, 0, stream>>>(deg, bsum);
    scan_pass2<<<1, 256, 0, stream>>>(bsum, boff, nb);
    scan_pass3<<<nb, 256, 0, stream>>>(deg, boff, rowptr, cursor);
    fill_adj<<<(E_TOT + 255) / 256, 256, 0, stream>>>(e_dm_src, e_dm_dst, e_am_src, e_am_dst,
                                                      cursor, adj);

    // ---- fold relation matrices (1 launch) ----
    {
        F4 f4{};
        f4.W[0] = Wk_d; f4.b[0] = bk_d; f4.a[0] = a_dm; f4.Wf[0] = Wf_k_dm; f4.bf[0] = bf_k_dm;
        f4.W[1] = Wv_d; f4.b[1] = bv_d; f4.a[1] = m_dm; f4.Wf[1] = Wf_v_dm; f4.bf[1] = bf_v_dm;
        f4.W[2] = Wk_a; f4.b[2] = bk_a; f4.a[2] = a_am; f4.Wf[2] = Wf_k_am; f4.bf[2] = bf_k_am;
        f4.W[3] = Wv_a; f4.b[3] = bv_a; f4.a[3] = m_am; f4.Wf[3] = Wf_v_am; f4.bf[3] = bf_v_am;
        fold_w4<<<dim3(257, 4), 256, 0, stream>>>(f4);
    }
    // ---- pack all B matrices to fragment order (1 launch) ----
    {
        PMulti pm{};
        pm.nd = 9;
        int b0 = 0;
        pm.d[0] = {W_in_m,  Bt_in_m, FIN, b0}; b0 += 32;
        pm.d[1] = {W_in_d,  Bt_in_d, FIN, b0}; b0 += 32;
        pm.d[2] = {W_in_a,  Bt_in_a, FIN, b0}; b0 += 32;
        pm.d[3] = {Wq_m,    Bt_q_m,  HID, b0}; b0 += 8;
        pm.d[4] = {Wf_k_dm, Bt_k_dm, HID, b0}; b0 += 8;
        pm.d[5] = {Wf_v_dm, Bt_v_dm, HID, b0}; b0 += 8;
        pm.d[6] = {Wf_k_am, Bt_k_am, HID, b0}; b0 += 8;
        pm.d[7] = {Wf_v_am, Bt_v_am, HID, b0}; b0 += 8;
        pm.d[8] = {Wa_m,    Bt_a_m,  HID, b0}; b0 += 8;
        wt_pack<<<b0, 256, 0, stream>>>(pm);
    }

    int bm_m = (NM + GBM - 1) / GBM;  // 782
    int bm_d = (ND + GBM - 1) / GBM;  // 157
    int bm_a = (NA + GBM - 1) / GBM;  // 391

    // launch (a): input proj + fused q/k/v second GEMMs
    {
        GMulti mu{};
        mu.nd = 3;
        mu.d[0] = {x_movie, Bt_in_m, b_in_m, h_m, nullptr, nullptr,
                   Bt_q_m, bq_m, q_m, nullptr, nullptr, nullptr,
                   NM, FIN, 0, 1, 0, 0, 0};
        mu.d[1] = {x_director, Bt_in_d, b_in_d, nullptr, nullptr, nullptr,
                   Bt_k_dm, bf_k_dm, kt_dm, Bt_v_dm, bf_v_dm, vt_dm,
                   ND, FIN, 0, 1, 0, 0, bm_m};
        mu.d[2] = {x_actor, Bt_in_a, b_in_a, nullptr, nullptr, nullptr,
                   Bt_k_am, bf_k_am, kt_am, Bt_v_am, bf_v_am, vt_am,
                   NA, FIN, 0, 1, 0, 0, bm_m + bm_d};
        gemm_mfma<<<bm_m + bm_d + bm_a, 512, 0, stream>>>(mu);
    }

    // fused per-destination aggregation (bf16 in/out)
    agg_fused<<<(NM + 3) / 4, 256, 0, stream>>>(rowptr, adj, q_m, kt_all, vt_all, p_dm, p_am, agg);

    // launch (c): out = beta*gelu(agg@Wa+ba)+(1-beta)*h_m, classifier fused -> d_out
    {
        GMulti mu{};
        mu.nd = 1;
        mu.d[0] = {agg, Bt_a_m, ba_m, nullptr, h_m, skip_m,
                   nullptr, W_out, d_out, nullptr, b_out, nullptr,
                   NM, HID, 1, 0, 1, 1, 0};
        gemm_mfma<<<bm_m, 512, 0, stream>>>(mu);
    }
}

// Round 16
// 383.309 us; speedup vs baseline: 1.3954x; 1.3954x over previous
//
#include <hip/hip_runtime.h>
#include <math.h>

// ---- problem constants ----
#define NM 50000
#define ND 10000
#define NA 25000
#define E_DM 150000
#define E_AM 300000
#define E_TOT (E_DM + E_AM)
#define HID 256
#define HEADS 8
#define HD 32
#define FIN 1024
#define SCALE 0.17677669529663687f  // 1/sqrt(32)

typedef __attribute__((ext_vector_type(8))) short short8;
typedef __attribute__((ext_vector_type(4))) float f32x4;

typedef __attribute__((address_space(1))) const unsigned char gas_u8;
typedef __attribute__((address_space(3))) unsigned char las_u8;

// async global->LDS 16B: global per-lane address, LDS wave-uniform base (+lane*16 by HW)
__device__ __forceinline__ void gload16(const void* g, void* l) {
    gas_u8* gp = (gas_u8*)(unsigned long long)(uintptr_t)g;
    las_u8* lp = (las_u8*)(unsigned int)(uintptr_t)l;
    __builtin_amdgcn_global_load_lds((const __attribute__((address_space(1))) void*)gp,
                                     (__attribute__((address_space(3))) void*)lp, 16, 0, 0);
}

// RNE f32 -> bf16
__device__ __forceinline__ unsigned int pk_bf16(float x, float y) {
    unsigned int a = __float_as_uint(x), b = __float_as_uint(y);
    a += 0x7FFFu + ((a >> 16) & 1u);
    b += 0x7FFFu + ((b >> 16) & 1u);
    return (a >> 16) | (b & 0xFFFF0000u);
}
__device__ __forceinline__ unsigned short to_bf16(float x) {
    unsigned int a = __float_as_uint(x);
    a += 0x7FFFu + ((a >> 16) & 1u);
    return (unsigned short)(a >> 16);
}
__device__ __forceinline__ float bf2f(unsigned short u) {
    return __uint_as_float(((unsigned int)u) << 16);
}

// ---- fold per-head relation matrix into W (4 descs in one launch) ----
struct F4 { const float* W[4]; const float* b[4]; const float* a[4]; float* Wf[4]; float* bf[4]; };
__global__ void fold_w4(F4 f4) {
    int di = blockIdx.y;
    const float* W = f4.W[di]; const float* b = f4.b[di]; const float* a = f4.a[di];
    float* Wf = f4.Wf[di]; float* bf = f4.bf[di];
    int c = threadIdx.x;
    int h = c >> 5, f = c & 31;
    int r = blockIdx.x;
    float acc = 0.f;
    if (r < HID) {
        #pragma unroll
        for (int d = 0; d < HD; ++d)
            acc += W[r * HID + h * HD + d] * a[(h * HD + d) * HD + f];
        Wf[r * HID + c] = acc;
    } else {
        #pragma unroll
        for (int d = 0; d < HD; ++d)
            acc += b[h * HD + d] * a[(h * HD + d) * HD + f];
        bf[c] = acc;
    }
}

// ---- pack W fp32 [K][256] -> bf16 fragment order [K/32][16 subtile][64 lane][8] ----
struct PDesc { const float* W; unsigned short* out; int K; int b0; };
struct PMulti { PDesc d[9]; int nd; };
__global__ void wt_pack(PMulti pm) {
    int bid = blockIdx.x; int di = 0;
    #pragma unroll
    for (int i = 1; i < 9; ++i) if (i < pm.nd && bid >= pm.d[i].b0) di = i;
    PDesc p = pm.d[di];
    int kstep = bid - p.b0;
    int t = threadIdx.x;
    #pragma unroll
    for (int i = 0; i < 32; ++i) {
        int idx = i * 256 + t;
        int n0 = idx >> 9, r = idx & 511, lane = r >> 3, j = r & 7;
        int k = kstep * 32 + (lane >> 4) * 8 + j;
        int c = n0 * 16 + (lane & 15);
        p.out[(size_t)kstep * 8192 + idx] = to_bf16(p.W[(size_t)k * HID + c]);
    }
}

// ---- multi-descriptor MFMA GEMM with fused second-GEMM / classifier epilogue ----
struct GDesc {
    const void* A; const unsigned short* Bt; const float* bias; void* C;
    const void* hskip; const float* gate;
    const unsigned short* Bt2; const float* bias2; void* C2;
    const unsigned short* Bt3; const float* bias3; void* C3;
    int M; int K; int epi; int obf; int abf; int cls; int b0;
};
struct GMulti { GDesc d[5]; int nd; };

#define GBM 64

__launch_bounds__(512, 6)
__global__ void gemm_mfma(GMulti mu) {
    __shared__ __align__(16) unsigned char smem[40960];
    unsigned short* sB0 = (unsigned short*)smem;            // 8192 elems (16KB)
    unsigned short* sB1 = sB0 + 8192;
    unsigned short* sA0 = (unsigned short*)(smem + 32768);  // 2048 elems (4KB)
    unsigned short* sA1 = sA0 + 2048;
    unsigned short* sHf = (unsigned short*)smem;            // 2nd-gemm A frags (32KB)
    float* arr = (float*)smem;                              // cls partials [2][64][4]

    int bid = blockIdx.x;
    int di = 0;
    #pragma unroll
    for (int i = 1; i < 5; ++i)
        if (i < mu.nd && bid >= mu.d[i].b0) di = i;
    GDesc g = mu.d[di];
    int bm = (bid - g.b0) * GBM;
    int M = g.M, K = g.K;

    int t = threadIdx.x;
    int lane = t & 63;
    int w = t >> 6;               // 0..7
    int wp = w >> 1;              // row subtile 0..3
    int ch = w & 1;               // col half 0..1
    int l16 = lane & 15;

    // fp32 A staging indices: thread t fills half a fragment slot
    int slot = t >> 1;            // 0..255
    int ss_ = slot >> 6;
    int sl  = slot & 63;
    int arow_f = bm + ss_ * 16 + (sl & 15);
    int ak0    = (sl >> 4) * 8 + (t & 1) * 4;
    const float* Ap = nullptr;
    const unsigned short* Abp = nullptr;
    if (g.abf) {
        if (w < 4) {
            int r = bm + w * 16 + l16;
            Abp = (const unsigned short*)g.A + (size_t)min(r, M - 1) * K + ((lane >> 4) * 8);
        }
    } else {
        Ap = (const float*)g.A + (size_t)min(arow_f, M - 1) * K + ak0;
    }

    f32x4 acc[8];
    #pragma unroll
    for (int n = 0; n < 8; ++n) acc[n] = (f32x4)(0.f);

    int nk = K >> 5;
    // prologue: stage step 0 into buf 0
    {
        const unsigned short* gB = g.Bt;
        gload16(gB + w * 512 + lane * 8, sB0 + w * 512);
        gload16(gB + (w + 8) * 512 + lane * 8, sB0 + (w + 8) * 512);
        if (g.abf) {
            if (w < 4) gload16(Abp, sA0 + w * 512);
        } else {
            float4 f = *(const float4*)(Ap);
            uint2 pk = make_uint2(pk_bf16(f.x, f.y), pk_bf16(f.z, f.w));
            *(uint2*)&sA0[slot * 8 + (t & 1) * 4] = pk;
        }
    }
    __syncthreads();

    int cur = 0;
    for (int ks = 0; ks < nk; ++ks) {
        unsigned short* sBc = cur ? sB1 : sB0;
        unsigned short* sAc = cur ? sA1 : sA0;
        unsigned short* dB  = cur ? sB0 : sB1;
        unsigned short* dA  = cur ? sA0 : sA1;
        bool pf = (ks + 1 < nk);
        float4 f;
        if (pf) {
            const unsigned short* gB = g.Bt + (size_t)(ks + 1) * 8192;
            gload16(gB + w * 512 + lane * 8, dB + w * 512);
            gload16(gB + (w + 8) * 512 + lane * 8, dB + (w + 8) * 512);
            if (g.abf) {
                if (w < 4) gload16(Abp + (ks + 1) * 32, dA + w * 512);
            } else {
                f = *(const float4*)(Ap + (ks + 1) * 32);
            }
        }
        short8 af = *(const short8*)&sAc[(wp * 64 + lane) * 8];
        short8 bfr[8];
        #pragma unroll
        for (int n = 0; n < 8; ++n)
            bfr[n] = *(const short8*)&sBc[((ch * 8 + n) * 64 + lane) * 8];
        #pragma unroll
        for (int n = 0; n < 8; ++n)
            acc[n] = __builtin_amdgcn_mfma_f32_16x16x32_bf16(af, bfr[n], acc[n], 0, 0, 0);
        if (pf && !g.abf) {
            uint2 pk = make_uint2(pk_bf16(f.x, f.y), pk_bf16(f.z, f.w));
            *(uint2*)&dA[slot * 8 + (t & 1) * 4] = pk;
        }
        __syncthreads();
        cur ^= 1;
    }

    // ---- epilogue ----
    float beta = 0.f;
    if (g.epi) beta = 1.f / (1.f + expf(-g.gate[0]));
    int r0 = bm + wp * 16 + ((lane >> 4) << 2);

    float pcl[4][4];
    if (g.cls) {
        #pragma unroll
        for (int j = 0; j < 4; ++j)
            #pragma unroll
            for (int c = 0; c < 4; ++c) pcl[j][c] = 0.f;
    }

    #pragma unroll
    for (int n = 0; n < 8; ++n) {
        int col = ch * 128 + n * 16 + l16;
        float4 wv;
        if (g.cls) wv = *(const float4*)(g.bias2 + col * 4);   // W_out row
        #pragma unroll
        for (int j = 0; j < 4; ++j) {
            int grow = r0 + j;
            float v = acc[n][j] + g.bias[col];
            if (g.epi) {
                float x = v;
                float gl = 0.5f * x * (1.f + tanhf(0.7978845608028654f * (x + 0.044715f * x * x * x)));
                float hv = bf2f(((const unsigned short*)g.hskip)[(size_t)min(grow, M - 1) * HID + col]);
                v = beta * gl + (1.f - beta) * hv;
            }
            if (g.cls) {
                pcl[j][0] += v * wv.x; pcl[j][1] += v * wv.y;
                pcl[j][2] += v * wv.z; pcl[j][3] += v * wv.w;
            } else {
                // scatter biased h into fragment order for the second GEMM
                int ks2 = ch * 4 + (n >> 1);
                int gg = ((n & 1) << 1) | ((lane & 15) >> 3);
                int l = ((lane >> 4) << 2) + j + (gg << 4);
                sHf[(((ks2 * 4) + wp) * 64 + l) * 8 + (lane & 7)] = to_bf16(v);
                if (g.C && grow < M)
                    ((unsigned short*)g.C)[(size_t)grow * HID + col] = to_bf16(v);
            }
        }
    }

    if (g.cls) {
        // reduce partials over the 16 lanes of each row group (fp32, exact layout)
        #pragma unroll
        for (int s = 1; s < 16; s <<= 1) {
            #pragma unroll
            for (int j = 0; j < 4; ++j)
                #pragma unroll
                for (int c = 0; c < 4; ++c)
                    pcl[j][c] += __shfl_xor(pcl[j][c], s);
        }
        if (l16 == 0) {
            int rb = wp * 16 + ((lane >> 4) << 2);
            #pragma unroll
            for (int j = 0; j < 4; ++j)
                #pragma unroll
                for (int c = 0; c < 4; ++c)
                    arr[((ch * 64) + rb + j) * 4 + c] = pcl[j][c];
        }
        __syncthreads();
        if (t < 256) {
            int row = t >> 2, c = t & 3;
            int grow = bm + row;
            if (grow < M) {
                float s = arr[(0 * 64 + row) * 4 + c] + arr[(1 * 64 + row) * 4 + c] + g.bias3[c];
                ((float*)g.C2)[(size_t)grow * 4 + c] = s;
            }
        }
    } else if (g.Bt2) {
        __syncthreads();   // h-tile fragments visible to all waves
        #pragma unroll 1
        for (int o = 0; o < 2; ++o) {
            const unsigned short* B2 = o ? g.Bt3 : g.Bt2;
            if (!B2) break;
            const float* bias2 = o ? g.bias3 : g.bias2;
            unsigned short* C2 = (unsigned short*)(o ? g.C3 : g.C2);
            f32x4 acc2[8];
            #pragma unroll
            for (int n = 0; n < 8; ++n) acc2[n] = (f32x4)(0.f);
            #pragma unroll 2
            for (int ks = 0; ks < 8; ++ks) {
                short8 af2 = *(const short8*)&sHf[(((ks * 4) + wp) * 64 + lane) * 8];
                #pragma unroll
                for (int n = 0; n < 8; ++n) {
                    short8 b2 = *(const short8*)(B2 + (size_t)ks * 8192 +
                                                 (size_t)(((ch * 8) + n) * 64 + lane) * 8);
                    acc2[n] = __builtin_amdgcn_mfma_f32_16x16x32_bf16(af2, b2, acc2[n], 0, 0, 0);
                }
            }
            #pragma unroll
            for (int n = 0; n < 8; ++n) {
                int col = ch * 128 + n * 16 + l16;
                #pragma unroll
                for (int j = 0; j < 4; ++j) {
                    int grow = r0 + j;
                    if (grow < M)
                        C2[(size_t)grow * HID + col] = to_bf16(acc2[n][j] + bias2[col]);
                }
            }
        }
    }
}

// ---- CSR build ----
__global__ void hist_deg(const int* __restrict__ dA, const int* __restrict__ dB,
                         int* __restrict__ deg) {
    int i = blockIdx.x * 256 + threadIdx.x;
    if (i < E_DM) atomicAdd(&deg[dA[i]], 1);
    else if (i < E_TOT) atomicAdd(&deg[dB[i - E_DM]], 1);
}

__global__ void scan_pass1(const int* __restrict__ deg, int* __restrict__ bsum) {
    __shared__ int s[256];
    int b = blockIdx.x, t = threadIdx.x;
    int i = b * 256 + t;
    int v = (i < NM) ? deg[i] : 0;
    s[t] = v; __syncthreads();
    for (int off = 128; off > 0; off >>= 1) {
        if (t < off) s[t] += s[t + off];
        __syncthreads();
    }
    if (t == 0) bsum[b] = s[0];
}

__global__ void scan_pass2(const int* __restrict__ bsum, int* __restrict__ boff, int nb) {
    __shared__ int s[256];
    int t = threadIdx.x;
    int v = (t < nb) ? bsum[t] : 0;
    s[t] = v; __syncthreads();
    for (int off = 1; off < 256; off <<= 1) {
        int x = (t >= off) ? s[t - off] : 0;
        __syncthreads();
        s[t] += x;
        __syncthreads();
    }
    if (t < nb) boff[t] = s[t] - v;   // exclusive
}

__global__ void scan_pass3(const int* __restrict__ deg, const int* __restrict__ boff,
                           int* __restrict__ rowptr, int* __restrict__ cursor) {
    __shared__ int s[256];
    int b = blockIdx.x, t = threadIdx.x, i = b * 256 + t;
    int v = (i < NM) ? deg[i] : 0;
    s[t] = v; __syncthreads();
    for (int off = 1; off < 256; off <<= 1) {
        int x = (t >= off) ? s[t - off] : 0;
        __syncthreads();
        s[t] += x;
        __syncthreads();
    }
    int excl = s[t] - v + boff[b];
    if (i < NM) { rowptr[i] = excl; cursor[i] = excl; }
    if (i == 0) rowptr[NM] = E_TOT;
}

__global__ void fill_adj(const int* __restrict__ sA, const int* __restrict__ dA,
                         const int* __restrict__ sB, const int* __restrict__ dB,
                         int* __restrict__ cursor, int* __restrict__ adj) {
    int i = blockIdx.x * 256 + threadIdx.x;
    int d, entry;
    if (i < E_DM)      { d = dA[i];        entry = sA[i]; }
    else if (i < E_TOT){ int j = i - E_DM; d = dB[j]; entry = (sB[j] + ND) | (1 << 16); }
    else return;
    int pos = atomicAdd(&cursor[d], 1);
    adj[pos] = entry;
}

// ---- fused per-destination attention aggregation: one wave per node (bf16 q/k/v, bf16 agg out) ----
__launch_bounds__(256)
__global__ void agg_fused(const int* __restrict__ rowptr, const int* __restrict__ adj,
                          const unsigned short* __restrict__ q, const unsigned short* __restrict__ kt_all,
                          const unsigned short* __restrict__ vt_all,
                          const float* __restrict__ p_dm, const float* __restrict__ p_am,
                          unsigned short* __restrict__ agg) {
    int d = blockIdx.x * 4 + (threadIdx.x >> 6);
    if (d >= NM) return;
    int lane = threadIdx.x & 63;
    int h = lane >> 3;                       // 8 lanes per head, 4 dims per lane
    int start = rowptr[d], end = rowptr[d + 1];
    uint2 qu = *(const uint2*)(q + (size_t)d * HID + lane * 4);
    float q0 = __uint_as_float(qu.x << 16), q1 = __uint_as_float(qu.x & 0xFFFF0000u);
    float q2 = __uint_as_float(qu.y << 16), q3 = __uint_as_float(qu.y & 0xFFFF0000u);
    float pr0 = p_dm[h] * SCALE, pr1 = p_am[h] * SCALE;
    float m = -INFINITY, den = 0.f, a0 = 0.f, a1 = 0.f, a2 = 0.f, a3 = 0.f;
    for (int i = start; i < end; ++i) {
        int e = adj[i];
        int sr = e & 0xFFFF;
        uint2 ku = *(const uint2*)(kt_all + (size_t)sr * HID + lane * 4);
        float k0 = __uint_as_float(ku.x << 16), k1 = __uint_as_float(ku.x & 0xFFFF0000u);
        float k2 = __uint_as_float(ku.y << 16), k3 = __uint_as_float(ku.y & 0xFFFF0000u);
        float prod = q0 * k0 + q1 * k1 + q2 * k2 + q3 * k3;
        prod += __shfl_xor(prod, 1);
        prod += __shfl_xor(prod, 2);
        prod += __shfl_xor(prod, 4);
        float a = prod * ((e >> 16) ? pr1 : pr0);
        float mn = fmaxf(m, a);
        float c  = __expf(m - mn);
        float ex = __expf(a - mn);
        uint2 vu = *(const uint2*)(vt_all + (size_t)sr * HID + lane * 4);
        float v0 = __uint_as_float(vu.x << 16), v1 = __uint_as_float(vu.x & 0xFFFF0000u);
        float v2 = __uint_as_float(vu.y << 16), v3 = __uint_as_float(vu.y & 0xFFFF0000u);
        den = den * c + ex;
        a0 = a0 * c + ex * v0; a1 = a1 * c + ex * v1;
        a2 = a2 * c + ex * v2; a3 = a3 * c + ex * v3;
        m = mn;
    }
    float inv = (end > start) ? 1.f / den : 0.f;
    *(uint2*)(agg + (size_t)d * HID + lane * 4) =
        make_uint2(pk_bf16(a0 * inv, a1 * inv), pk_bf16(a2 * inv, a3 * inv));
}

extern "C" void kernel_launch(void* const* d_in, const int* in_sizes, int n_in,
                              void* d_out, int out_size, void* d_ws, size_t ws_size,
                              hipStream_t stream) {
    (void)in_sizes; (void)n_in; (void)out_size; (void)ws_size;
    const float* x_movie    = (const float*)d_in[0];
    const float* x_director = (const float*)d_in[1];
    const float* x_actor    = (const float*)d_in[2];
    const int*   e_dm_src = (const int*)d_in[8];
    const int*   e_dm_dst = (const int*)d_in[9];
    const float* a_dm     = (const float*)d_in[10];
    const float* m_dm     = (const float*)d_in[11];
    const float* p_dm     = (const float*)d_in[12];
    const int*   e_am_src = (const int*)d_in[18];
    const int*   e_am_dst = (const int*)d_in[19];
    const float* a_am     = (const float*)d_in[20];
    const float* m_am     = (const float*)d_in[21];
    const float* p_am     = (const float*)d_in[22];
    const float* W_in_m = (const float*)d_in[23];
    const float* b_in_m = (const float*)d_in[24];
    const float* Wq_m   = (const float*)d_in[27];
    const float* bq_m   = (const float*)d_in[28];
    const float* Wa_m   = (const float*)d_in[31];
    const float* ba_m   = (const float*)d_in[32];
    const float* skip_m = (const float*)d_in[33];
    const float* W_in_d = (const float*)d_in[34];
    const float* b_in_d = (const float*)d_in[35];
    const float* Wk_d   = (const float*)d_in[36];
    const float* bk_d   = (const float*)d_in[37];
    const float* Wv_d   = (const float*)d_in[40];
    const float* bv_d   = (const float*)d_in[41];
    const float* W_in_a = (const float*)d_in[45];
    const float* b_in_a = (const float*)d_in[46];
    const float* Wk_a   = (const float*)d_in[47];
    const float* bk_a   = (const float*)d_in[48];
    const float* Wv_a   = (const float*)d_in[51];
    const float* bv_a   = (const float*)d_in[52];
    const float* W_out  = (const float*)d_in[56];
    const float* b_out  = (const float*)d_in[57];

    // ---- workspace layout (byte cursor, 256B aligned) ----
    char* base = (char*)d_ws;
    size_t off = 0;
    auto alloc = [&](size_t bytes) -> void* {
        void* p = base + off;
        off = (off + bytes + 255) & ~(size_t)255;
        return p;
    };
    unsigned short* h_m = (unsigned short*)alloc((size_t)NM * HID * 2);   // bf16
    unsigned short* q_m = (unsigned short*)alloc((size_t)NM * HID * 2);   // bf16
    unsigned short* agg = (unsigned short*)alloc((size_t)NM * HID * 2);   // bf16
    unsigned short* kt_all = (unsigned short*)alloc((size_t)(ND + NA) * HID * 2);
    unsigned short* vt_all = (unsigned short*)alloc((size_t)(ND + NA) * HID * 2);
    float* Wf     = (float*)alloc(4 * (size_t)HID * HID * 4);
    float* bf     = (float*)alloc(4 * (size_t)HID * 4);
    int* deg      = (int*)alloc(NM * 4);
    int* rowptr   = (int*)alloc((NM + 1) * 4);
    int* cursor   = (int*)alloc(NM * 4);
    int* bsum     = (int*)alloc(256 * 4);
    int* boff     = (int*)alloc(256 * 4);
    int* adj      = (int*)alloc((size_t)E_TOT * 4);
    unsigned short* Bt_in_m = (unsigned short*)alloc((size_t)256 * 1024 * 2);
    unsigned short* Bt_in_d = (unsigned short*)alloc((size_t)256 * 1024 * 2);
    unsigned short* Bt_in_a = (unsigned short*)alloc((size_t)256 * 1024 * 2);
    unsigned short* Bt_q_m  = (unsigned short*)alloc((size_t)256 * 256 * 2);
    unsigned short* Bt_k_dm = (unsigned short*)alloc((size_t)256 * 256 * 2);
    unsigned short* Bt_v_dm = (unsigned short*)alloc((size_t)256 * 256 * 2);
    unsigned short* Bt_k_am = (unsigned short*)alloc((size_t)256 * 256 * 2);
    unsigned short* Bt_v_am = (unsigned short*)alloc((size_t)256 * 256 * 2);
    unsigned short* Bt_a_m  = (unsigned short*)alloc((size_t)256 * 256 * 2);

    unsigned short* kt_dm = kt_all;
    unsigned short* kt_am = kt_all + (size_t)ND * HID;
    unsigned short* vt_dm = vt_all;
    unsigned short* vt_am = vt_all + (size_t)ND * HID;

    float* Wf_k_dm = Wf + 0 * HID * HID;  float* bf_k_dm = bf + 0 * HID;
    float* Wf_v_dm = Wf + 1 * HID * HID;  float* bf_v_dm = bf + 1 * HID;
    float* Wf_k_am = Wf + 2 * HID * HID;  float* bf_k_am = bf + 2 * HID;
    float* Wf_v_am = Wf + 3 * HID * HID;  float* bf_v_am = bf + 3 * HID;

    // ---- CSR build ----
    hipMemsetAsync(deg, 0, NM * sizeof(int), stream);
    hist_deg<<<(E_TOT + 255) / 256, 256, 0, stream>>>(e_dm_dst, e_am_dst, deg);
    int nb = (NM + 255) / 256;  // 196
    scan_pass1<<<nb, 256, 0, stream>>>(deg, bsum);
    scan_pass2<<<1, 256, 0, stream>>>(bsum, boff, nb);
    scan_pass3<<<nb, 256, 0, stream>>>(deg, boff, rowptr, cursor);
    fill_adj<<<(E_TOT + 255) / 256, 256, 0, stream>>>(e_dm_src, e_dm_dst, e_am_src, e_am_dst,
                                                      cursor, adj);

    // ---- fold relation matrices (1 launch) ----
    {
        F4 f4{};
        f4.W[0] = Wk_d; f4.b[0] = bk_d; f4.a[0] = a_dm; f4.Wf[0] = Wf_k_dm; f4.bf[0] = bf_k_dm;
        f4.W[1] = Wv_d; f4.b[1] = bv_d; f4.a[1] = m_dm; f4.Wf[1] = Wf_v_dm; f4.bf[1] = bf_v_dm;
        f4.W[2] = Wk_a; f4.b[2] = bk_a; f4.a[2] = a_am; f4.Wf[2] = Wf_k_am; f4.bf[2] = bf_k_am;
        f4.W[3] = Wv_a; f4.b[3] = bv_a; f4.a[3] = m_am; f4.Wf[3] = Wf_v_am; f4.bf[3] = bf_v_am;
        fold_w4<<<dim3(257, 4), 256, 0, stream>>>(f4);
    }
    // ---- pack all B matrices to fragment order (1 launch) ----
    {
        PMulti pm{};
        pm.nd = 9;
        int b0 = 0;
        pm.d[0] = {W_in_m,  Bt_in_m, FIN, b0}; b0 += 32;
        pm.d[1] = {W_in_d,  Bt_in_d, FIN, b0}; b0 += 32;
        pm.d[2] = {W_in_a,  Bt_in_a, FIN, b0}; b0 += 32;
        pm.d[3] = {Wq_m,    Bt_q_m,  HID, b0}; b0 += 8;
        pm.d[4] = {Wf_k_dm, Bt_k_dm, HID, b0}; b0 += 8;
        pm.d[5] = {Wf_v_dm, Bt_v_dm, HID, b0}; b0 += 8;
        pm.d[6] = {Wf_k_am, Bt_k_am, HID, b0}; b0 += 8;
        pm.d[7] = {Wf_v_am, Bt_v_am, HID, b0}; b0 += 8;
        pm.d[8] = {Wa_m,    Bt_a_m,  HID, b0}; b0 += 8;
        wt_pack<<<b0, 256, 0, stream>>>(pm);
    }

    int bm_m = (NM + GBM - 1) / GBM;  // 782
    int bm_d = (ND + GBM - 1) / GBM;  // 157
    int bm_a = (NA + GBM - 1) / GBM;  // 391

    // launch (a): input proj + fused q/k/v second GEMMs
    {
        GMulti mu{};
        mu.nd = 3;
        mu.d[0] = {x_movie, Bt_in_m, b_in_m, h_m, nullptr, nullptr,
                   Bt_q_m, bq_m, q_m, nullptr, nullptr, nullptr,
                   NM, FIN, 0, 1, 0, 0, 0};
        mu.d[1] = {x_director, Bt_in_d, b_in_d, nullptr, nullptr, nullptr,
                   Bt_k_dm, bf_k_dm, kt_dm, Bt_v_dm, bf_v_dm, vt_dm,
                   ND, FIN, 0, 1, 0, 0, bm_m};
        mu.d[2] = {x_actor, Bt_in_a, b_in_a, nullptr, nullptr, nullptr,
                   Bt_k_am, bf_k_am, kt_am, Bt_v_am, bf_v_am, vt_am,
                   NA, FIN, 0, 1, 0, 0, bm_m + bm_d};
        gemm_mfma<<<bm_m + bm_d + bm_a, 512, 0, stream>>>(mu);
    }

    // fused per-destination aggregation (bf16 in/out)
    agg_fused<<<(NM + 3) / 4, 256, 0, stream>>>(rowptr, adj, q_m, kt_all, vt_all, p_dm, p_am, agg);

    // launch (c): out = beta*gelu(agg@Wa+ba)+(1-beta)*h_m, classifier fused -> d_out
    {
        GMulti mu{};
        mu.nd = 1;
        mu.d[0] = {agg, Bt_a_m, ba_m, nullptr, h_m, skip_m,
                   nullptr, W_out, d_out, nullptr, b_out, nullptr,
                   NM, HID, 1, 0, 1, 1, 0};
        gemm_mfma<<<bm_m, 512, 0, stream>>>(mu);
    }
}

// Round 17
// 357.919 us; speedup vs baseline: 1.4944x; 1.0709x over previous
//
#include <hip/hip_runtime.h>
#include <math.h>

// ---- problem constants ----
#define NM 50000
#define ND 10000
#define NA 25000
#define E_DM 150000
#define E_AM 300000
#define E_TOT (E_DM + E_AM)
#define HID 256
#define HEADS 8
#define HD 32
#define FIN 1024
#define SCALE 0.17677669529663687f  // 1/sqrt(32)

typedef __attribute__((ext_vector_type(8))) short short8;
typedef __attribute__((ext_vector_type(4))) float f32x4;

typedef __attribute__((address_space(1))) const unsigned char gas_u8;
typedef __attribute__((address_space(3))) unsigned char las_u8;

// async global->LDS 16B: global per-lane address, LDS wave-uniform base (+lane*16 by HW)
__device__ __forceinline__ void gload16(const void* g, void* l) {
    gas_u8* gp = (gas_u8*)(unsigned long long)(uintptr_t)g;
    las_u8* lp = (las_u8*)(unsigned int)(uintptr_t)l;
    __builtin_amdgcn_global_load_lds((const __attribute__((address_space(1))) void*)gp,
                                     (__attribute__((address_space(3))) void*)lp, 16, 0, 0);
}

// RNE f32 -> bf16
__device__ __forceinline__ unsigned int pk_bf16(float x, float y) {
    unsigned int a = __float_as_uint(x), b = __float_as_uint(y);
    a += 0x7FFFu + ((a >> 16) & 1u);
    b += 0x7FFFu + ((b >> 16) & 1u);
    return (a >> 16) | (b & 0xFFFF0000u);
}
__device__ __forceinline__ unsigned short to_bf16(float x) {
    unsigned int a = __float_as_uint(x);
    a += 0x7FFFu + ((a >> 16) & 1u);
    return (unsigned short)(a >> 16);
}
__device__ __forceinline__ float bf2f(unsigned short u) {
    return __uint_as_float(((unsigned int)u) << 16);
}

// ---- fold per-head relation matrix into W (4 descs in one launch) ----
struct F4 { const float* W[4]; const float* b[4]; const float* a[4]; float* Wf[4]; float* bf[4]; };
__global__ void fold_w4(F4 f4) {
    int di = blockIdx.y;
    const float* W = f4.W[di]; const float* b = f4.b[di]; const float* a = f4.a[di];
    float* Wf = f4.Wf[di]; float* bf = f4.bf[di];
    int c = threadIdx.x;
    int h = c >> 5, f = c & 31;
    int r = blockIdx.x;
    float acc = 0.f;
    if (r < HID) {
        #pragma unroll
        for (int d = 0; d < HD; ++d)
            acc += W[r * HID + h * HD + d] * a[(h * HD + d) * HD + f];
        Wf[r * HID + c] = acc;
    } else {
        #pragma unroll
        for (int d = 0; d < HD; ++d)
            acc += b[h * HD + d] * a[(h * HD + d) * HD + f];
        bf[c] = acc;
    }
}

// ---- pack W fp32 [K][256] -> bf16 fragment order [K/32][16 subtile][64 lane][8] ----
struct PDesc { const float* W; unsigned short* out; int K; int b0; };
struct PMulti { PDesc d[9]; int nd; };
__global__ void wt_pack(PMulti pm) {
    int bid = blockIdx.x; int di = 0;
    #pragma unroll
    for (int i = 1; i < 9; ++i) if (i < pm.nd && bid >= pm.d[i].b0) di = i;
    PDesc p = pm.d[di];
    int kstep = bid - p.b0;
    int t = threadIdx.x;
    #pragma unroll
    for (int i = 0; i < 32; ++i) {
        int idx = i * 256 + t;
        int n0 = idx >> 9, r = idx & 511, lane = r >> 3, j = r & 7;
        int k = kstep * 32 + (lane >> 4) * 8 + j;
        int c = n0 * 16 + (lane & 15);
        p.out[(size_t)kstep * 8192 + idx] = to_bf16(p.W[(size_t)k * HID + c]);
    }
}

// ---- multi-descriptor MFMA GEMM with fused second-GEMM / classifier epilogue ----
// Main: C[M,256] = A[M,K]@B + bias (BM=64, BN=256, 8 waves, B dbuf via gload_lds
// 2x16KB, A dbuf 2x4KB, one __syncthreads per K-step).
// Epilogue (non-cls): scatter biased h-tile (bf16, fragment order) into LDS;
//   second GEMM(s) vs fragment-packed B2/B3 straight from L2 -> C2/C3.
// Epilogue (cls): fold out-tile into d_out via fp32 partials + shfl reduce.
struct GDesc {
    const void* A; const unsigned short* Bt; const float* bias; void* C;
    const void* hskip; const float* gate;
    const unsigned short* Bt2; const float* bias2; void* C2;
    const unsigned short* Bt3; const float* bias3; void* C3;
    int M; int K; int epi; int obf; int abf; int cls; int b0;
};
struct GMulti { GDesc d[5]; int nd; };

#define GBM 64

__launch_bounds__(512, 6)
__global__ void gemm_mfma(GMulti mu) {
    __shared__ __align__(16) unsigned char smem[40960];
    unsigned short* sB0 = (unsigned short*)smem;            // 8192 elems (16KB)
    unsigned short* sB1 = sB0 + 8192;
    unsigned short* sA0 = (unsigned short*)(smem + 32768);  // 2048 elems (4KB)
    unsigned short* sA1 = sA0 + 2048;
    unsigned short* sHf = (unsigned short*)smem;            // 2nd-gemm A frags (32KB)
    float* arr = (float*)smem;                              // cls partials [2][64][4]

    int bid = blockIdx.x;
    int di = 0;
    #pragma unroll
    for (int i = 1; i < 5; ++i)
        if (i < mu.nd && bid >= mu.d[i].b0) di = i;
    GDesc g = mu.d[di];
    int bm = (bid - g.b0) * GBM;
    int M = g.M, K = g.K;

    int t = threadIdx.x;
    int lane = t & 63;
    int w = t >> 6;               // 0..7
    int wp = w >> 1;              // row subtile 0..3
    int ch = w & 1;               // col half 0..1
    int l16 = lane & 15;

    // fp32 A staging indices: thread t fills half a fragment slot
    int slot = t >> 1;            // 0..255
    int ss_ = slot >> 6;
    int sl  = slot & 63;
    int arow_f = bm + ss_ * 16 + (sl & 15);
    int ak0    = (sl >> 4) * 8 + (t & 1) * 4;
    const float* Ap = nullptr;
    const unsigned short* Abp = nullptr;
    if (g.abf) {
        if (w < 4) {
            int r = bm + w * 16 + l16;
            Abp = (const unsigned short*)g.A + (size_t)min(r, M - 1) * K + ((lane >> 4) * 8);
        }
    } else {
        Ap = (const float*)g.A + (size_t)min(arow_f, M - 1) * K + ak0;
    }

    f32x4 acc[8];
    #pragma unroll
    for (int n = 0; n < 8; ++n) acc[n] = (f32x4)(0.f);

    int nk = K >> 5;
    // prologue: stage step 0 into buf 0
    {
        const unsigned short* gB = g.Bt;
        gload16(gB + w * 512 + lane * 8, sB0 + w * 512);
        gload16(gB + (w + 8) * 512 + lane * 8, sB0 + (w + 8) * 512);
        if (g.abf) {
            if (w < 4) gload16(Abp, sA0 + w * 512);
        } else {
            float4 f = *(const float4*)(Ap);
            uint2 pk = make_uint2(pk_bf16(f.x, f.y), pk_bf16(f.z, f.w));
            *(uint2*)&sA0[slot * 8 + (t & 1) * 4] = pk;
        }
    }
    __syncthreads();

    int cur = 0;
    for (int ks = 0; ks < nk; ++ks) {
        unsigned short* sBc = cur ? sB1 : sB0;
        unsigned short* sAc = cur ? sA1 : sA0;
        unsigned short* dB  = cur ? sB0 : sB1;
        unsigned short* dA  = cur ? sA0 : sA1;
        bool pf = (ks + 1 < nk);
        float4 f;
        if (pf) {
            const unsigned short* gB = g.Bt + (size_t)(ks + 1) * 8192;
            gload16(gB + w * 512 + lane * 8, dB + w * 512);
            gload16(gB + (w + 8) * 512 + lane * 8, dB + (w + 8) * 512);
            if (g.abf) {
                if (w < 4) gload16(Abp + (ks + 1) * 32, dA + w * 512);
            } else {
                f = *(const float4*)(Ap + (ks + 1) * 32);
            }
        }
        short8 af = *(const short8*)&sAc[(wp * 64 + lane) * 8];
        short8 bfr[8];
        #pragma unroll
        for (int n = 0; n < 8; ++n)
            bfr[n] = *(const short8*)&sBc[((ch * 8 + n) * 64 + lane) * 8];
        #pragma unroll
        for (int n = 0; n < 8; ++n)
            acc[n] = __builtin_amdgcn_mfma_f32_16x16x32_bf16(af, bfr[n], acc[n], 0, 0, 0);
        if (pf && !g.abf) {
            uint2 pk = make_uint2(pk_bf16(f.x, f.y), pk_bf16(f.z, f.w));
            *(uint2*)&dA[slot * 8 + (t & 1) * 4] = pk;
        }
        __syncthreads();
        cur ^= 1;
    }

    // ---- epilogue ----
    float beta = 0.f;
    if (g.epi) beta = 1.f / (1.f + expf(-g.gate[0]));
    int r0 = bm + wp * 16 + ((lane >> 4) << 2);

    float pcl[4][4];
    if (g.cls) {
        #pragma unroll
        for (int j = 0; j < 4; ++j)
            #pragma unroll
            for (int c = 0; c < 4; ++c) pcl[j][c] = 0.f;
    }

    #pragma unroll
    for (int n = 0; n < 8; ++n) {
        int col = ch * 128 + n * 16 + l16;
        float4 wv;
        if (g.cls) wv = *(const float4*)(g.bias2 + col * 4);   // W_out row
        #pragma unroll
        for (int j = 0; j < 4; ++j) {
            int grow = r0 + j;
            float v = acc[n][j] + g.bias[col];
            if (g.epi) {
                float x = v;
                float gl = 0.5f * x * (1.f + tanhf(0.7978845608028654f * (x + 0.044715f * x * x * x)));
                float hv = bf2f(((const unsigned short*)g.hskip)[(size_t)min(grow, M - 1) * HID + col]);
                v = beta * gl + (1.f - beta) * hv;
            }
            if (g.cls) {
                pcl[j][0] += v * wv.x; pcl[j][1] += v * wv.y;
                pcl[j][2] += v * wv.z; pcl[j][3] += v * wv.w;
            } else {
                // scatter biased h into fragment order for the second GEMM
                int ks2 = ch * 4 + (n >> 1);
                int gg = ((n & 1) << 1) | ((lane & 15) >> 3);
                int l = ((lane >> 4) << 2) + j + (gg << 4);
                sHf[(((ks2 * 4) + wp) * 64 + l) * 8 + (lane & 7)] = to_bf16(v);
                if (g.C && grow < M)
                    ((unsigned short*)g.C)[(size_t)grow * HID + col] = to_bf16(v);
            }
        }
    }

    if (g.cls) {
        // reduce partials over the 16 lanes of each row group (fp32, exact layout)
        #pragma unroll
        for (int s = 1; s < 16; s <<= 1) {
            #pragma unroll
            for (int j = 0; j < 4; ++j)
                #pragma unroll
                for (int c = 0; c < 4; ++c)
                    pcl[j][c] += __shfl_xor(pcl[j][c], s);
        }
        if (l16 == 0) {
            int rb = wp * 16 + ((lane >> 4) << 2);
            #pragma unroll
            for (int j = 0; j < 4; ++j)
                #pragma unroll
                for (int c = 0; c < 4; ++c)
                    arr[((ch * 64) + rb + j) * 4 + c] = pcl[j][c];
        }
        __syncthreads();
        if (t < 256) {
            int row = t >> 2, c = t & 3;
            int grow = bm + row;
            if (grow < M) {
                float s = arr[(0 * 64 + row) * 4 + c] + arr[(1 * 64 + row) * 4 + c] + g.bias3[c];
                ((float*)g.C2)[(size_t)grow * 4 + c] = s;
            }
        }
    } else if (g.Bt2) {
        __syncthreads();   // h-tile fragments visible to all waves
        #pragma unroll 1
        for (int o = 0; o < 2; ++o) {
            const unsigned short* B2 = o ? g.Bt3 : g.Bt2;
            if (!B2) break;
            const float* bias2 = o ? g.bias3 : g.bias2;
            unsigned short* C2 = (unsigned short*)(o ? g.C3 : g.C2);
            f32x4 acc2[8];
            #pragma unroll
            for (int n = 0; n < 8; ++n) acc2[n] = (f32x4)(0.f);
            #pragma unroll 1
            for (int ks = 0; ks < 8; ++ks) {
                short8 af2 = *(const short8*)&sHf[(((ks * 4) + wp) * 64 + lane) * 8];
                #pragma unroll
                for (int n = 0; n < 8; ++n) {
                    short8 b2 = *(const short8*)(B2 + (size_t)ks * 8192 +
                                                 (size_t)(((ch * 8) + n) * 64 + lane) * 8);
                    acc2[n] = __builtin_amdgcn_mfma_f32_16x16x32_bf16(af2, b2, acc2[n], 0, 0, 0);
                }
            }
            #pragma unroll
            for (int n = 0; n < 8; ++n) {
                int col = ch * 128 + n * 16 + l16;
                #pragma unroll
                for (int j = 0; j < 4; ++j) {
                    int grow = r0 + j;
                    if (grow < M)
                        C2[(size_t)grow * HID + col] = to_bf16(acc2[n][j] + bias2[col]);
                }
            }
        }
    }
}

// ---- CSR build ----
__global__ void hist_deg(const int* __restrict__ dA, const int* __restrict__ dB,
                         int* __restrict__ deg) {
    int i = blockIdx.x * 256 + threadIdx.x;
    if (i < E_DM) atomicAdd(&deg[dA[i]], 1);
    else if (i < E_TOT) atomicAdd(&deg[dB[i - E_DM]], 1);
}

__global__ void scan_pass1(const int* __restrict__ deg, int* __restrict__ bsum) {
    __shared__ int s[256];
    int b = blockIdx.x, t = threadIdx.x;
    int i = b * 256 + t;
    int v = (i < NM) ? deg[i] : 0;
    s[t] = v; __syncthreads();
    for (int off = 128; off > 0; off >>= 1) {
        if (t < off) s[t] += s[t + off];
        __syncthreads();
    }
    if (t == 0) bsum[b] = s[0];
}

__global__ void scan_pass2(const int* __restrict__ bsum, int* __restrict__ boff, int nb) {
    __shared__ int s[256];
    int t = threadIdx.x;
    int v = (t < nb) ? bsum[t] : 0;
    s[t] = v; __syncthreads();
    for (int off = 1; off < 256; off <<= 1) {
        int x = (t >= off) ? s[t - off] : 0;
        __syncthreads();
        s[t] += x;
        __syncthreads();
    }
    if (t < nb) boff[t] = s[t] - v;   // exclusive
}

__global__ void scan_pass3(const int* __restrict__ deg, const int* __restrict__ boff,
                           int* __restrict__ rowptr, int* __restrict__ cursor) {
    __shared__ int s[256];
    int b = blockIdx.x, t = threadIdx.x, i = b * 256 + t;
    int v = (i < NM) ? deg[i] : 0;
    s[t] = v; __syncthreads();
    for (int off = 1; off < 256; off <<= 1) {
        int x = (t >= off) ? s[t - off] : 0;
        __syncthreads();
        s[t] += x;
        __syncthreads();
    }
    int excl = s[t] - v + boff[b];
    if (i < NM) { rowptr[i] = excl; cursor[i] = excl; }
    if (i == 0) rowptr[NM] = E_TOT;
}

__global__ void fill_adj(const int* __restrict__ sA, const int* __restrict__ dA,
                         const int* __restrict__ sB, const int* __restrict__ dB,
                         int* __restrict__ cursor, int* __restrict__ adj) {
    int i = blockIdx.x * 256 + threadIdx.x;
    int d, entry;
    if (i < E_DM)      { d = dA[i];        entry = sA[i]; }
    else if (i < E_TOT){ int j = i - E_DM; d = dB[j]; entry = (sB[j] + ND) | (1 << 16); }
    else return;
    int pos = atomicAdd(&cursor[d], 1);
    adj[pos] = entry;
}

// ---- fused per-destination attention aggregation: one wave per node (bf16 q/k/v, bf16 agg out) ----
__launch_bounds__(256)
__global__ void agg_fused(const int* __restrict__ rowptr, const int* __restrict__ adj,
                          const unsigned short* __restrict__ q, const unsigned short* __restrict__ kt_all,
                          const unsigned short* __restrict__ vt_all,
                          const float* __restrict__ p_dm, const float* __restrict__ p_am,
                          unsigned short* __restrict__ agg) {
    int d = blockIdx.x * 4 + (threadIdx.x >> 6);
    if (d >= NM) return;
    int lane = threadIdx.x & 63;
    int h = lane >> 3;                       // 8 lanes per head, 4 dims per lane
    int start = rowptr[d], end = rowptr[d + 1];
    uint2 qu = *(const uint2*)(q + (size_t)d * HID + lane * 4);
    float q0 = __uint_as_float(qu.x << 16), q1 = __uint_as_float(qu.x & 0xFFFF0000u);
    float q2 = __uint_as_float(qu.y << 16), q3 = __uint_as_float(qu.y & 0xFFFF0000u);
    float pr0 = p_dm[h] * SCALE, pr1 = p_am[h] * SCALE;
    float m = -INFINITY, den = 0.f, a0 = 0.f, a1 = 0.f, a2 = 0.f, a3 = 0.f;
    for (int i = start; i < end; ++i) {
        int e = adj[i];
        int sr = e & 0xFFFF;
        uint2 ku = *(const uint2*)(kt_all + (size_t)sr * HID + lane * 4);
        float k0 = __uint_as_float(ku.x << 16), k1 = __uint_as_float(ku.x & 0xFFFF0000u);
        float k2 = __uint_as_float(ku.y << 16), k3 = __uint_as_float(ku.y & 0xFFFF0000u);
        float prod = q0 * k0 + q1 * k1 + q2 * k2 + q3 * k3;
        prod += __shfl_xor(prod, 1);
        prod += __shfl_xor(prod, 2);
        prod += __shfl_xor(prod, 4);
        float a = prod * ((e >> 16) ? pr1 : pr0);
        float mn = fmaxf(m, a);
        float c  = __expf(m - mn);
        float ex = __expf(a - mn);
        uint2 vu = *(const uint2*)(vt_all + (size_t)sr * HID + lane * 4);
        float v0 = __uint_as_float(vu.x << 16), v1 = __uint_as_float(vu.x & 0xFFFF0000u);
        float v2 = __uint_as_float(vu.y << 16), v3 = __uint_as_float(vu.y & 0xFFFF0000u);
        den = den * c + ex;
        a0 = a0 * c + ex * v0; a1 = a1 * c + ex * v1;
        a2 = a2 * c + ex * v2; a3 = a3 * c + ex * v3;
        m = mn;
    }
    float inv = (end > start) ? 1.f / den : 0.f;
    *(uint2*)(agg + (size_t)d * HID + lane * 4) =
        make_uint2(pk_bf16(a0 * inv, a1 * inv), pk_bf16(a2 * inv, a3 * inv));
}

extern "C" void kernel_launch(void* const* d_in, const int* in_sizes, int n_in,
                              void* d_out, int out_size, void* d_ws, size_t ws_size,
                              hipStream_t stream) {
    (void)in_sizes; (void)n_in; (void)out_size; (void)ws_size;
    const float* x_movie    = (const float*)d_in[0];
    const float* x_director = (const float*)d_in[1];
    const float* x_actor    = (const float*)d_in[2];
    const int*   e_dm_src = (const int*)d_in[8];
    const int*   e_dm_dst = (const int*)d_in[9];
    const float* a_dm     = (const float*)d_in[10];
    const float* m_dm     = (const float*)d_in[11];
    const float* p_dm     = (const float*)d_in[12];
    const int*   e_am_src = (const int*)d_in[18];
    const int*   e_am_dst = (const int*)d_in[19];
    const float* a_am     = (const float*)d_in[20];
    const float* m_am     = (const float*)d_in[21];
    const float* p_am     = (const float*)d_in[22];
    const float* W_in_m = (const float*)d_in[23];
    const float* b_in_m = (const float*)d_in[24];
    const float* Wq_m   = (const float*)d_in[27];
    const float* bq_m   = (const float*)d_in[28];
    const float* Wa_m   = (const float*)d_in[31];
    const float* ba_m   = (const float*)d_in[32];
    const float* skip_m = (const float*)d_in[33];
    const float* W_in_d = (const float*)d_in[34];
    const float* b_in_d = (const float*)d_in[35];
    const float* Wk_d   = (const float*)d_in[36];
    const float* bk_d   = (const float*)d_in[37];
    const float* Wv_d   = (const float*)d_in[40];
    const float* bv_d   = (const float*)d_in[41];
    const float* W_in_a = (const float*)d_in[45];
    const float* b_in_a = (const float*)d_in[46];
    const float* Wk_a   = (const float*)d_in[47];
    const float* bk_a   = (const float*)d_in[48];
    const float* Wv_a   = (const float*)d_in[51];
    const float* bv_a   = (const float*)d_in[52];
    const float* W_out  = (const float*)d_in[56];
    const float* b_out  = (const float*)d_in[57];

    // ---- workspace layout (byte cursor, 256B aligned) ----
    char* base = (char*)d_ws;
    size_t off = 0;
    auto alloc = [&](size_t bytes) -> void* {
        void* p = base + off;
        off = (off + bytes + 255) & ~(size_t)255;
        return p;
    };
    unsigned short* h_m = (unsigned short*)alloc((size_t)NM * HID * 2);   // bf16
    unsigned short* q_m = (unsigned short*)alloc((size_t)NM * HID * 2);   // bf16
    unsigned short* agg = (unsigned short*)alloc((size_t)NM * HID * 2);   // bf16
    unsigned short* kt_all = (unsigned short*)alloc((size_t)(ND + NA) * HID * 2);
    unsigned short* vt_all = (unsigned short*)alloc((size_t)(ND + NA) * HID * 2);
    float* Wf     = (float*)alloc(4 * (size_t)HID * HID * 4);
    float* bf     = (float*)alloc(4 * (size_t)HID * 4);
    int* deg      = (int*)alloc(NM * 4);
    int* rowptr   = (int*)alloc((NM + 1) * 4);
    int* cursor   = (int*)alloc(NM * 4);
    int* bsum     = (int*)alloc(256 * 4);
    int* boff     = (int*)alloc(256 * 4);
    int* adj      = (int*)alloc((size_t)E_TOT * 4);
    unsigned short* Bt_in_m = (unsigned short*)alloc((size_t)256 * 1024 * 2);
    unsigned short* Bt_in_d = (unsigned short*)alloc((size_t)256 * 1024 * 2);
    unsigned short* Bt_in_a = (unsigned short*)alloc((size_t)256 * 1024 * 2);
    unsigned short* Bt_q_m  = (unsigned short*)alloc((size_t)256 * 256 * 2);
    unsigned short* Bt_k_dm = (unsigned short*)alloc((size_t)256 * 256 * 2);
    unsigned short* Bt_v_dm = (unsigned short*)alloc((size_t)256 * 256 * 2);
    unsigned short* Bt_k_am = (unsigned short*)alloc((size_t)256 * 256 * 2);
    unsigned short* Bt_v_am = (unsigned short*)alloc((size_t)256 * 256 * 2);
    unsigned short* Bt_a_m  = (unsigned short*)alloc((size_t)256 * 256 * 2);

    unsigned short* kt_dm = kt_all;
    unsigned short* kt_am = kt_all + (size_t)ND * HID;
    unsigned short* vt_dm = vt_all;
    unsigned short* vt_am = vt_all + (size_t)ND * HID;

    float* Wf_k_dm = Wf + 0 * HID * HID;  float* bf_k_dm = bf + 0 * HID;
    float* Wf_v_dm = Wf + 1 * HID * HID;  float* bf_v_dm = bf + 1 * HID;
    float* Wf_k_am = Wf + 2 * HID * HID;  float* bf_k_am = bf + 2 * HID;
    float* Wf_v_am = Wf + 3 * HID * HID;  float* bf_v_am = bf + 3 * HID;

    // ---- CSR build ----
    hipMemsetAsync(deg, 0, NM * sizeof(int), stream);
    hist_deg<<<(E_TOT + 255) / 256, 256, 0, stream>>>(e_dm_dst, e_am_dst, deg);
    int nb = (NM + 255) / 256;  // 196
    scan_pass1<<<nb, 256, 0, stream>>>(deg, bsum);
    scan_pass2<<<1, 256, 0, stream>>>(bsum, boff, nb);
    scan_pass3<<<nb, 256, 0, stream>>>(deg, boff, rowptr, cursor);
    fill_adj<<<(E_TOT + 255) / 256, 256, 0, stream>>>(e_dm_src, e_dm_dst, e_am_src, e_am_dst,
                                                      cursor, adj);

    // ---- fold relation matrices (1 launch) ----
    {
        F4 f4{};
        f4.W[0] = Wk_d; f4.b[0] = bk_d; f4.a[0] = a_dm; f4.Wf[0] = Wf_k_dm; f4.bf[0] = bf_k_dm;
        f4.W[1] = Wv_d; f4.b[1] = bv_d; f4.a[1] = m_dm; f4.Wf[1] = Wf_v_dm; f4.bf[1] = bf_v_dm;
        f4.W[2] = Wk_a; f4.b[2] = bk_a; f4.a[2] = a_am; f4.Wf[2] = Wf_k_am; f4.bf[2] = bf_k_am;
        f4.W[3] = Wv_a; f4.b[3] = bv_a; f4.a[3] = m_am; f4.Wf[3] = Wf_v_am; f4.bf[3] = bf_v_am;
        fold_w4<<<dim3(257, 4), 256, 0, stream>>>(f4);
    }
    // ---- pack all B matrices to fragment order (1 launch) ----
    {
        PMulti pm{};
        pm.nd = 9;
        int b0 = 0;
        pm.d[0] = {W_in_m,  Bt_in_m, FIN, b0}; b0 += 32;
        pm.d[1] = {W_in_d,  Bt_in_d, FIN, b0}; b0 += 32;
        pm.d[2] = {W_in_a,  Bt_in_a, FIN, b0}; b0 += 32;
        pm.d[3] = {Wq_m,    Bt_q_m,  HID, b0}; b0 += 8;
        pm.d[4] = {Wf_k_dm, Bt_k_dm, HID, b0}; b0 += 8;
        pm.d[5] = {Wf_v_dm, Bt_v_dm, HID, b0}; b0 += 8;
        pm.d[6] = {Wf_k_am, Bt_k_am, HID, b0}; b0 += 8;
        pm.d[7] = {Wf_v_am, Bt_v_am, HID, b0}; b0 += 8;
        pm.d[8] = {Wa_m,    Bt_a_m,  HID, b0}; b0 += 8;
        wt_pack<<<b0, 256, 0, stream>>>(pm);
    }

    int bm_m = (NM + GBM - 1) / GBM;  // 782
    int bm_d = (ND + GBM - 1) / GBM;  // 157
    int bm_a = (NA + GBM - 1) / GBM;  // 391

    // launch (a): input proj + fused q/k/v second GEMMs
    {
        GMulti mu{};
        mu.nd = 3;
        mu.d[0] = {x_movie, Bt_in_m, b_in_m, h_m, nullptr, nullptr,
                   Bt_q_m, bq_m, q_m, nullptr, nullptr, nullptr,
                   NM, FIN, 0, 1, 0, 0, 0};
        mu.d[1] = {x_director, Bt_in_d, b_in_d, nullptr, nullptr, nullptr,
                   Bt_k_dm, bf_k_dm, kt_dm, Bt_v_dm, bf_v_dm, vt_dm,
                   ND, FIN, 0, 1, 0, 0, bm_m};
        mu.d[2] = {x_actor, Bt_in_a, b_in_a, nullptr, nullptr, nullptr,
                   Bt_k_am, bf_k_am, kt_am, Bt_v_am, bf_v_am, vt_am,
                   NA, FIN, 0, 1, 0, 0, bm_m + bm_d};
        gemm_mfma<<<bm_m + bm_d + bm_a, 512, 0, stream>>>(mu);
    }

    // fused per-destination aggregation (bf16 in/out)
    agg_fused<<<(NM + 3) / 4, 256, 0, stream>>>(rowptr, adj, q_m, kt_all, vt_all, p_dm, p_am, agg);

    // launch (c): out = beta*gelu(agg@Wa+ba)+(1-beta)*h_m, classifier fused -> d_out
    {
        GMulti mu{};
        mu.nd = 1;
        mu.d[0] = {agg, Bt_a_m, ba_m, nullptr, h_m, skip_m,
                   nullptr, W_out, d_out, nullptr, b_out, nullptr,
                   NM, HID, 1, 0, 1, 1, 0};
        gemm_mfma<<<bm_m, 512, 0, stream>>>(mu);
    }
}